// Round 7
// baseline (423.426 us; speedup 1.0000x reference)
//
#include <hip/hip_runtime.h>
#include <stdint.h>

#define BATCH 16384
#define DDIM  3072
#define NK    300
#define NKP   320
#define NCLS  10

#define BM 32
#define BK 64
#define KT (DDIM / BK)   // 48

typedef __bf16 bf16x8 __attribute__((ext_vector_type(8)));
typedef float  f32x16 __attribute__((ext_vector_type(16)));

__device__ __forceinline__ unsigned f2bf(float f) {
  unsigned u = __float_as_uint(f);
  u += 0x7FFFu + ((u >> 16) & 1u);   // RNE
  return u >> 16;
}

// ---------------------------------------------------------------- prep_w ----
// w5 (300x3072 f32) -> wn bf16 (320x3072, rows 300..319 zero), rw[k]=1/(|w|+eps)
__global__ __launch_bounds__(256) void prep_w_kernel(
    const float* __restrict__ w5, unsigned short* __restrict__ wn,
    float* __restrict__ rw, float* __restrict__ gsum, float* __restrict__ gsq) {
  const int r = blockIdx.x;
  const int t = threadIdx.x;
  if (r == 0) {  // zero stat accumulators (gemm runs after this kernel)
    for (int i = t; i < NKP; i += 256) { gsum[i] = 0.f; gsq[i] = 0.f; }
  }
  unsigned long long* dst = (unsigned long long*)(wn + (size_t)r * DDIM);
  if (r < NK) {
    const float4* src = (const float4*)(w5 + (size_t)r * DDIM);
    float ss = 0.f;
#pragma unroll
    for (int i = 0; i < 3; ++i) {
      float4 v = src[t + i * 256];
      ss += v.x * v.x + v.y * v.y + v.z * v.z + v.w * v.w;
      unsigned lo = f2bf(v.x) | (f2bf(v.y) << 16);
      unsigned hi = f2bf(v.z) | (f2bf(v.w) << 16);
      dst[t + i * 256] = (unsigned long long)lo | ((unsigned long long)hi << 32);
    }
#pragma unroll
    for (int m = 1; m <= 32; m <<= 1) ss += __shfl_xor(ss, m, 64);
    __shared__ float red[4];
    if ((t & 63) == 0) red[t >> 6] = ss;
    __syncthreads();
    if (t == 0) {
      float tot = red[0] + red[1] + red[2] + red[3];
      rw[r] = 1.f / (sqrtf(tot) + 1e-12f);
    }
  } else {
#pragma unroll
    for (int i = 0; i < 3; ++i) dst[t + i * 256] = 0ull;
    if (t == 0) rw[r] = 0.f;
  }
}

// ------------------------------------------------------------------ gemm ----
// fc5[m][n] = relu( (x[m]. wn[n]) * rx[m] * rw[n] ), plus per-n sum/sumsq atomics.
// 640 threads = 10 waves; wave w owns the 32x32 output tile at cols [w*32,w*32+32).
// B (wn, 1.9 MB, L2-resident) is loaded DIRECTLY global->VGPR: no LDS staging,
// no barrier-drain serialization, no bank conflicts. Only x staged in LDS (4 KB).
// grid=512 -> 2 blocks/CU = 20 waves/CU for latency hiding.
__global__ __launch_bounds__(640, 5) void gemm_kernel(
    const float* __restrict__ x, const unsigned short* __restrict__ wn,
    const float* __restrict__ rw, float* __restrict__ fc5,
    float* __restrict__ gsum, float* __restrict__ gsq) {
  __shared__ alignas(16) unsigned short xs[BM * BK];   // 4 KB, XOR-swizzled
  __shared__ float rxs[BM];

  const int tid  = threadIdx.x;
  const int lane = tid & 63;
  const int w    = tid >> 6;          // wave 0..9
  const int m0   = (int)blockIdx.x * BM;

  // ---- x staging map (threads 0..511): row = t>>4, 4-float segment t&15 ----
  const int srow = tid >> 4;          // 0..31
  const int sseg = tid & 15;          // float4 index within 64-col tile
  const float* xsrc = x + (size_t)(m0 + srow) * DDIM + sseg * 4;
  // 8B write; swizzle on 16B chunks: chunk = sseg>>1, half = sseg&1
  const int wbyte = srow * 128 + ((((sseg >> 1) ^ (srow & 7))) << 4) + ((sseg & 1) << 3);

  // ---- B direct-from-global base: col-major-over-rows layout of wn ----
  const int r31   = lane & 31;
  const int khalf = lane >> 5;
  const int ng    = w * 32 + r31;     // global output col 0..319
  const unsigned short* bbase = wn + (size_t)ng * DDIM + khalf * 8;

  // ---- A fragment address (xs, swizzled) ----
  const char* abase = (const char*)xs + (size_t)r31 * 128;
  const int aswz = r31 & 7;

  f32x16 acc = {};
  float ss = 0.f;

  float4 v;
  if (tid < 512) v = *(const float4*)xsrc;

  for (int kt = 0; kt < KT; ++kt) {
    // ---- stage x (fp32 -> bf16, accumulate row sumsq) ----
    if (tid < 512) {
      ss += v.x * v.x + v.y * v.y + v.z * v.z + v.w * v.w;
      unsigned lo = f2bf(v.x) | (f2bf(v.y) << 16);
      unsigned hi = f2bf(v.z) | (f2bf(v.w) << 16);
      *(unsigned long long*)((char*)xs + wbyte) =
          (unsigned long long)lo | ((unsigned long long)hi << 32);
    }
    __syncthreads();
    // prefetch next x tile (consumed after next barrier; latency hides under MFMA)
    if (kt + 1 < KT && tid < 512) v = *(const float4*)(xsrc + (size_t)(kt + 1) * BK);
    // ---- B fragments straight from global (L2-hit after warmup) ----
    const unsigned short* bk = bbase + (size_t)kt * BK;
    bf16x8 b0 = *(const bf16x8*)(bk + 0 * 16);
    bf16x8 b1 = *(const bf16x8*)(bk + 1 * 16);
    bf16x8 b2 = *(const bf16x8*)(bk + 2 * 16);
    bf16x8 b3 = *(const bf16x8*)(bk + 3 * 16);
    // ---- A fragments from LDS ----
    bf16x8 a0 = *(const bf16x8*)(abase + (((0 * 2 + khalf) ^ aswz) << 4));
    bf16x8 a1 = *(const bf16x8*)(abase + (((1 * 2 + khalf) ^ aswz) << 4));
    bf16x8 a2 = *(const bf16x8*)(abase + (((2 * 2 + khalf) ^ aswz) << 4));
    bf16x8 a3 = *(const bf16x8*)(abase + (((3 * 2 + khalf) ^ aswz) << 4));
    acc = __builtin_amdgcn_mfma_f32_32x32x16_bf16(a0, b0, acc, 0, 0, 0);
    acc = __builtin_amdgcn_mfma_f32_32x32x16_bf16(a1, b1, acc, 0, 0, 0);
    acc = __builtin_amdgcn_mfma_f32_32x32x16_bf16(a2, b2, acc, 0, 0, 0);
    acc = __builtin_amdgcn_mfma_f32_32x32x16_bf16(a3, b3, acc, 0, 0, 0);
    __syncthreads();                   // xs reuse guard
  }

  // ---- inverse x-row norms (16 threads per row, consecutive lanes) ----
  if (tid < 512) {
    ss += __shfl_xor(ss, 1, 64);
    ss += __shfl_xor(ss, 2, 64);
    ss += __shfl_xor(ss, 4, 64);
    ss += __shfl_xor(ss, 8, 64);
    if ((tid & 15) == 0) rxs[srow] = 1.f / (sqrtf(ss) + 1e-12f);
  }
  __syncthreads();

  // ---- epilogue: scale, relu, store fc5, per-channel stats ----
  const int kh4 = khalf * 4;
  const float rwv = (ng < NK) ? rw[ng] : 0.f;
  float s = 0.f, q = 0.f;
#pragma unroll
  for (int r = 0; r < 16; ++r) {
    const int row = (r & 3) + 8 * (r >> 2) + kh4;
    float vv = acc[r] * rxs[row] * rwv;
    vv = fmaxf(vv, 0.f);
    if (ng < NK) fc5[(size_t)(m0 + row) * NK + ng] = vv;
    s += vv; q += vv * vv;
  }
  s += __shfl_xor(s, 32, 64);
  q += __shfl_xor(q, 32, 64);
  if (lane < 32 && ng < NK) {
    atomicAdd(&gsum[ng], s);
    atomicAdd(&gsq[ng], q);
  }
}

// ---------------------------------------------------------------- bn+fc6 ----
// Finalizes stats per block (redundant, cheap), applies BN, 300->10 readout.
__global__ __launch_bounds__(256) void bn_fc6_kernel(
    const float* __restrict__ fc5, const float* __restrict__ w6,
    const float* __restrict__ gamma, const float* __restrict__ beta,
    const float* __restrict__ gsum, const float* __restrict__ gsq,
    float* __restrict__ bn5, float* __restrict__ fc6) {
  __shared__ float w6s[NCLS * NK];
  __shared__ float scs[NK], shs[NK];
  const int t = threadIdx.x;
  for (int i = t; i < NCLS * NK; i += 256) w6s[i] = w6[i];
  for (int i = t; i < NK; i += 256) {
    const float invB = 1.f / (float)BATCH;
    float mean = gsum[i] * invB;
    float var  = gsq[i] * invB - mean * mean;
    var = fmaxf(var, 0.f);
    float sc = gamma[i] * rsqrtf(var + 1e-5f);
    scs[i] = sc;
    shs[i] = beta[i] - mean * sc;
  }
  __syncthreads();
  const int wv = t >> 6, l = t & 63;
  const int r = (int)blockIdx.x * 4 + wv;
  const float* frow = fc5 + (size_t)r * NK;
  float* brow = bn5 + (size_t)r * NK;
  float accv[NCLS];
#pragma unroll
  for (int o = 0; o < NCLS; ++o) accv[o] = 0.f;
#pragma unroll
  for (int i = 0; i < 5; ++i) {
    const int k = i * 64 + l;
    if (k < NK) {
      float b = frow[k] * scs[k] + shs[k];
      brow[k] = b;
#pragma unroll
      for (int o = 0; o < NCLS; ++o) accv[o] += b * w6s[o * NK + k];
    }
  }
#pragma unroll
  for (int o = 0; o < NCLS; ++o) {
    float v = accv[o];
#pragma unroll
    for (int m = 1; m <= 32; m <<= 1) v += __shfl_xor(v, m, 64);
    if (l == 0) fc6[(size_t)r * NCLS + o] = v;
  }
}

// ---------------------------------------------------------------- launch ----
extern "C" void kernel_launch(void* const* d_in, const int* in_sizes, int n_in,
                              void* d_out, int out_size, void* d_ws, size_t ws_size,
                              hipStream_t stream) {
  const float* x     = (const float*)d_in[0];
  const float* w5    = (const float*)d_in[1];
  const float* gamma = (const float*)d_in[2];
  const float* beta  = (const float*)d_in[3];
  const float* w6    = (const float*)d_in[4];

  float* fc5 = (float*)d_out;
  float* bn5 = fc5 + (size_t)BATCH * NK;
  float* fc6 = bn5 + (size_t)BATCH * NK;

  char* ws = (char*)d_ws;
  unsigned short* wn = (unsigned short*)ws;                 // 320*3072*2 B
  float* rw   = (float*)(ws + (size_t)NKP * DDIM * 2);
  float* gsum = rw + NKP;
  float* gsq  = gsum + NKP;

  hipLaunchKernelGGL(prep_w_kernel, dim3(NKP), dim3(256), 0, stream,
                     w5, wn, rw, gsum, gsq);
  hipLaunchKernelGGL(gemm_kernel, dim3(BATCH / BM), dim3(640), 0, stream,
                     x, wn, rw, fc5, gsum, gsq);
  hipLaunchKernelGGL(bn_fc6_kernel, dim3(BATCH / 4), dim3(256), 0, stream,
                     fc5, w6, gamma, beta, gsum, gsq, bn5, fc6);
}